// Round 1
// baseline (329.648 us; speedup 1.0000x reference)
//
#include <hip/hip_runtime.h>

typedef unsigned short u16;
typedef __attribute__((ext_vector_type(8))) short short8;
typedef __attribute__((ext_vector_type(4))) float f32x4;

#define NF 2
#define NV 4
#define FV 8
#define NE 2048
#define NIN 512
#define NOUT 512
#define NM 514

// ws layout (bytes)
#define WS_POW     0u        // 4 floats: p1, p2sum, p3sum
#define WS_COLMIN  1024u     // 512 f (as int bits)
#define WS_G       3072u     // 514 f
#define WS_GN      6144u     // 512 f
#define WS_ETA     8192u     // 512 float4
#define WS_DENOM   16384u    // 8*512 f
#define WS_BIASZ   32768u    // 8*512 f
#define WS_BIAST   49152u    // 8*512 f
#define WS_THETA   65536u    // 514*512 f
#define WS_GT      1118208u  // 514*512 f
#define WS_ABF     2170880u  // 8*2048*512 u16
#define WS_BZT     18948096u // 8*512*512 u16 (n-major: [fv][n][k])
#define WS_BTT     23142400u // same

__constant__ float c_etas[4][4] = {
    {0.05f, 0.90f, 0.20f, 8.0f},
    {0.10f, 0.80f, 0.30f, 5.0f},
    {0.00f, 1.00f, 0.25f, 10.0f},
    {0.15f, 0.70f, 0.15f, 6.0f}};

__device__ __forceinline__ u16 f2bf(float x) {
    unsigned u = __float_as_uint(x);
    unsigned r = (u + 0x7fffu + ((u >> 16) & 1u)) >> 16;
    return (u16)r;
}

__device__ __forceinline__ void gll16(const void* g, void* l) {
    __builtin_amdgcn_global_load_lds((__attribute__((address_space(1))) void*)g,
                                     (__attribute__((address_space(3))) void*)l,
                                     16, 0, 0);
}

// ---- k1b: theta forward value + per-column min of g_init ----
__global__ void k_theta(const float* __restrict__ theta_, float* __restrict__ theta_t,
                        int* __restrict__ colmin) {
    int idx = blockIdx.x * 256 + threadIdx.x;
    if (idx >= NM * NOUT) return;
    int n = idx & (NOUT - 1);
    float th = theta_[idx];
    float thc = fminf(fmaxf(th, -10.f), 10.f);
    float gi = fabsf(thc);
    float tht = (gi < 0.01f) ? 0.f : thc;
    theta_t[idx] = tht;
    atomicMin(&colmin[n], __float_as_int(gi));  // gi >= 0: int order == float order
}

// ---- k1c: g_tilde + row sums G[m] + col sums Gn[n] ----
__global__ void k_gtilde(const float* __restrict__ theta_, const int* __restrict__ colmin,
                         float* __restrict__ g_tilde, float* __restrict__ G,
                         float* __restrict__ Gn) {
    int idx = blockIdx.x * 256 + threadIdx.x;
    if (idx >= NM * NOUT) return;
    int n = idx & (NOUT - 1);
    int m = idx >> 9;
    float thc = fminf(fmaxf(theta_[idx], -10.f), 10.f);
    float gi = fabsf(thc);
    float gt = gi * (1e-4f / __int_as_float(colmin[n]));
    g_tilde[idx] = gt;
    atomicAdd(&Gn[n], gt);
    // whole block shares one m (512 cols / 256 threads aligned)
    __shared__ float red[256];
    red[threadIdx.x] = gt;
    __syncthreads();
    for (int s = 128; s > 0; s >>= 1) {
        if (threadIdx.x < s) red[threadIdx.x] += red[threadIdx.x + s];
        __syncthreads();
    }
    if (threadIdx.x == 0) atomicAdd(&G[m], red[0]);
}

// ---- k1d: gumbel argmax -> per-column activation params ----
__global__ void k_etasel(const float* __restrict__ coeff, const float* __restrict__ gumb,
                         float4* __restrict__ eta4) {
    int n = blockIdx.x * 256 + threadIdx.x;
    if (n >= NOUT) return;
    float best = -1e30f;
    int bi = 0;
    for (int i = 0; i < 4; i++) {
        float c = fminf(fmaxf(coeff[i * NOUT + n], -1.f), 1.f);
        float u = gumb[i * NOUT + n];
        float g = -logf(-logf(u + 1e-20f) + 1e-20f);
        float v = c + g;
        if (v > best) { best = v; bi = i; }
    }
    eta4[n] = make_float4(c_etas[bi][0], c_etas[bi][1], c_etas[bi][2], c_etas[bi][3]);
}

// ---- k2a: denom[fv][n] = sum_m |theta_t[m,n] * fac| ----
__global__ void k_denom(const float* __restrict__ theta_t, const float* __restrict__ noise,
                        float* __restrict__ denom) {
    int fv = blockIdx.z, mc = blockIdx.y, nc = blockIdx.x;
    int t = threadIdx.x;
    int nl = t & 63, mg = t >> 6;
    int n = nc * 64 + nl;
    int mbase = mc * 128 + mg * 32;
    float acc = 0.f;
    for (int i = 0; i < 32; i++) {
        int m = mbase + i;
        if (m < NM) {
            float fac = noise[(fv * NM + m) * NOUT + n] * 0.2f + 0.9f;
            acc += fabsf(theta_t[m * NOUT + n] * fac);
        }
    }
    __shared__ float red[256];
    red[t] = acc;
    __syncthreads();
    if (t < 64)
        atomicAdd(&denom[fv * NOUT + n], red[t] + red[t + 64] + red[t + 128] + red[t + 192]);
}

// ---- k2b: build transposed bf16 B-matrices + fp32 bias rows ----
__global__ void k_wmat(const float* __restrict__ theta_t, const float* __restrict__ g_tilde,
                       const float* __restrict__ noise, const float* __restrict__ denom,
                       u16* __restrict__ BzT, u16* __restrict__ BtT,
                       float* __restrict__ bias_z, float* __restrict__ bias_t) {
    int fv = blockIdx.z, mt = blockIdx.y, nt = blockIdx.x;
    int t = threadIdx.x;
    int nl = t & 63, rg = t >> 6;
    __shared__ u16 Wl[64][68];
    __shared__ u16 Sl[64][68];
    int n = nt * 64 + nl;
    float rdv = 1.f / (denom[fv * NOUT + n] + 1e-10f);
    for (int r = 0; r < 16; r++) {
        int ml = rg * 16 + r;
        int m = mt * 64 + ml;
        if (m < 513) {
            float fac = noise[(fv * NM + m) * NOUT + n] * 0.2f + 0.9f;
            float th = theta_t[m * NOUT + n] * fac;
            float sg = (th >= 0.f) ? 1.f : -1.f;
            float gt = g_tilde[m * NOUT + n];
            if (m == 512) {
                bias_z[fv * NOUT + n] = th * rdv;
                bias_t[fv * NOUT + n] = sg * gt;
            } else {
                Wl[ml][nl] = f2bf(th * rdv);
                Sl[ml][nl] = f2bf(sg * gt);
            }
        }
    }
    __syncthreads();
    if (mt < 8) {
        for (int r = 0; r < 16; r++) {
            int nl2 = rg * 16 + r;
            int ml2 = t & 63;
            int gidx = (fv * NOUT + nt * 64 + nl2) * NIN + mt * 64 + ml2;
            BzT[gidx] = Wl[ml2][nl2];
            BtT[gidx] = Sl[ml2][nl2];
        }
    }
}

// ---- k3: convert A to bf16 + p1 partial (sum a^2 * G[k]) ----
__global__ void k_prepA(const float* __restrict__ a_prev, const float* __restrict__ G,
                        u16* __restrict__ Abf, float* __restrict__ pow_acc) {
    int idx = blockIdx.x * 256 + threadIdx.x;  // 2,097,152 float4s
    float4 v = ((const float4*)a_prev)[idx];
    int k = (idx & 127) << 2;
    float4 g4 = *((const float4*)(G + k));
    float acc = v.x * v.x * g4.x + v.y * v.y * g4.y + v.z * v.z * g4.z + v.w * v.w * g4.w;
    ushort4 o;
    o.x = f2bf(v.x); o.y = f2bf(v.y); o.z = f2bf(v.z); o.w = f2bf(v.w);
    ((ushort4*)Abf)[idx] = o;
    for (int off = 32; off > 0; off >>= 1) acc += __shfl_down(acc, off);
    __shared__ float red[4];
    int lane = threadIdx.x & 63, wv = threadIdx.x >> 6;
    if (lane == 0) red[wv] = acc;
    __syncthreads();
    if (threadIdx.x == 0) atomicAdd(&pow_acc[0], red[0] + red[1] + red[2] + red[3]);
}

// ---- k4: fused dual-B MFMA GEMM + activation epilogue + power reductions ----
__global__ __launch_bounds__(256, 2) void k_gemm(
    const u16* __restrict__ Abf, const u16* __restrict__ BzT, const u16* __restrict__ BtT,
    const float* __restrict__ bias_z, const float* __restrict__ bias_t,
    const float* __restrict__ Gn, const float4* __restrict__ eta4,
    float* __restrict__ out, float* __restrict__ pow_acc) {
    __shared__ alignas(16) u16 As[128 * 32];
    __shared__ alignas(16) u16 Bzs[128 * 32];
    __shared__ alignas(16) u16 Bts[128 * 32];
    const int tid = threadIdx.x;
    const int lane = tid & 63;
    const int wv = tid >> 6;
    const int wr = wv >> 1, wc = wv & 1;
    const int fv = blockIdx.z;
    const int e0 = blockIdx.y * 128;
    const int n0 = blockIdx.x * 128;

    const u16* Ag = Abf + (fv * NE + e0) * NIN;
    const u16* Bzg = BzT + (fv * NOUT + n0) * NIN;
    const u16* Btg = BtT + (fv * NOUT + n0) * NIN;

    f32x4 accz[4][4], acct[4][4];
#pragma unroll
    for (int i = 0; i < 4; i++)
#pragma unroll
        for (int j = 0; j < 4; j++) {
            f32x4 zz = {0.f, 0.f, 0.f, 0.f};
            accz[i][j] = zz;
            acct[i][j] = zz;
        }

    const int r0 = tid >> 2;        // staging row 0..63
    const int c0 = (tid & 3) * 8;   // k-chunk element offset

    for (int k0 = 0; k0 < 512; k0 += 32) {
        gll16(Ag + r0 * 512 + k0 + c0, (u16*)As + tid * 8);
        gll16(Ag + (r0 + 64) * 512 + k0 + c0, (u16*)As + tid * 8 + 2048);
        gll16(Bzg + r0 * 512 + k0 + c0, (u16*)Bzs + tid * 8);
        gll16(Bzg + (r0 + 64) * 512 + k0 + c0, (u16*)Bzs + tid * 8 + 2048);
        gll16(Btg + r0 * 512 + k0 + c0, (u16*)Bts + tid * 8);
        gll16(Btg + (r0 + 64) * 512 + k0 + c0, (u16*)Bts + tid * 8 + 2048);
        __builtin_amdgcn_s_waitcnt(0);
        __syncthreads();
        const int kof = (lane >> 4) * 8;
        const int rA = wr * 64 + (lane & 15);
        const int rB = wc * 64 + (lane & 15);
        short8 af[4], bzf[4], btf[4];
#pragma unroll
        for (int i = 0; i < 4; i++) af[i] = *(const short8*)(As + (rA + i * 16) * 32 + kof);
#pragma unroll
        for (int j = 0; j < 4; j++) {
            bzf[j] = *(const short8*)(Bzs + (rB + j * 16) * 32 + kof);
            btf[j] = *(const short8*)(Bts + (rB + j * 16) * 32 + kof);
        }
#pragma unroll
        for (int i = 0; i < 4; i++)
#pragma unroll
            for (int j = 0; j < 4; j++) {
                accz[i][j] = __builtin_amdgcn_mfma_f32_16x16x32_bf16(af[i], bzf[j], accz[i][j], 0, 0, 0);
                acct[i][j] = __builtin_amdgcn_mfma_f32_16x16x32_bf16(af[i], btf[j], acct[i][j], 0, 0, 0);
            }
        __syncthreads();
    }

    // epilogue: C/D layout col=lane&15, row=(lane>>4)*4+reg (m89-verified)
    float p2 = 0.f, p3 = 0.f;
    const int col = lane & 15;
    const int rowq = (lane >> 4) * 4;
#pragma unroll
    for (int j = 0; j < 4; j++) {
        int n = n0 + wc * 64 + j * 16 + col;
        float bz = bias_z[fv * NOUT + n];
        float bt = bias_t[fv * NOUT + n];
        float gnv = Gn[n];
        float4 e4 = eta4[n];
#pragma unroll
        for (int i = 0; i < 4; i++) {
            int ebase = e0 + wr * 64 + i * 16 + rowq;
#pragma unroll
            for (int r = 0; r < 4; r++) {
                float z = accz[i][j][r] + bz;
                float t = acct[i][j][r] + bt;
                p2 += z * t;
                p3 += z * z * gnv;
                float x = (z - e4.z) * e4.w;
                float ex = __expf(2.f * x);
                float th = 1.f - 2.f / (ex + 1.f);
                out[(fv * NE + ebase + r) * NOUT + n] = e4.x + e4.y * th;
            }
        }
    }
    for (int off = 32; off > 0; off >>= 1) {
        p2 += __shfl_down(p2, off);
        p3 += __shfl_down(p3, off);
    }
    if (lane == 0) {
        atomicAdd(&pow_acc[1], p2);
        atomicAdd(&pow_acc[2], p3);
    }
}

// ---- k5: combine power terms ----
__global__ void k_final(const float* __restrict__ pow_acc, const float* __restrict__ G,
                        float* __restrict__ out) {
    if (threadIdx.x == 0) {
        float mp = (pow_acc[0] + 16384.f * G[512] - 2.f * pow_acc[1] + pow_acc[2]) * (1.f / 16384.f);
        out[8388608] = mp;
    }
}

extern "C" void kernel_launch(void* const* d_in, const int* in_sizes, int n_in,
                              void* d_out, int out_size, void* d_ws, size_t ws_size,
                              hipStream_t stream) {
    const float* a_prev = (const float*)d_in[0];
    const float* theta_ = (const float*)d_in[1];
    const float* coeff = (const float*)d_in[2];
    const float* noise = (const float*)d_in[3];
    const float* gumb = (const float*)d_in[4];
    float* out = (float*)d_out;
    char* w = (char*)d_ws;
    float* pow_acc = (float*)(w + WS_POW);
    int* colmin = (int*)(w + WS_COLMIN);
    float* G = (float*)(w + WS_G);
    float* Gn = (float*)(w + WS_GN);
    float4* eta4 = (float4*)(w + WS_ETA);
    float* denom = (float*)(w + WS_DENOM);
    float* bias_z = (float*)(w + WS_BIASZ);
    float* bias_t = (float*)(w + WS_BIAST);
    float* theta_t = (float*)(w + WS_THETA);
    float* g_tilde = (float*)(w + WS_GT);
    u16* Abf = (u16*)(w + WS_ABF);
    u16* BzT = (u16*)(w + WS_BZT);
    u16* BtT = (u16*)(w + WS_BTT);

    hipMemsetAsync(pow_acc, 0, 16, stream);
    hipMemsetAsync(colmin, 0x7f, 2048, stream);  // 0x7f7f7f7f = 3.39e38 (positive float max-ish)
    hipMemsetAsync(G, 0, NM * 4, stream);
    hipMemsetAsync(Gn, 0, NOUT * 4, stream);
    hipMemsetAsync(denom, 0, FV * NOUT * 4, stream);

    k_theta<<<1028, 256, 0, stream>>>(theta_, theta_t, colmin);
    k_gtilde<<<1028, 256, 0, stream>>>(theta_, colmin, g_tilde, G, Gn);
    k_etasel<<<2, 256, 0, stream>>>(coeff, gumb, eta4);
    k_denom<<<dim3(8, 5, FV), 256, 0, stream>>>(theta_t, noise, denom);
    k_wmat<<<dim3(8, 9, FV), 256, 0, stream>>>(theta_t, g_tilde, noise, denom, BzT, BtT, bias_z, bias_t);
    k_prepA<<<8192, 256, 0, stream>>>(a_prev, G, Abf, pow_acc);
    k_gemm<<<dim3(4, 16, FV), 256, 0, stream>>>(Abf, BzT, BtT, bias_z, bias_t, Gn, eta4, out, pow_acc);
    k_final<<<1, 64, 0, stream>>>(pow_acc, G, out);
}

// Round 2
// 257.608 us; speedup vs baseline: 1.2797x; 1.2797x over previous
//
#include <hip/hip_runtime.h>

typedef unsigned short u16;
typedef __attribute__((ext_vector_type(8))) short short8;
typedef __attribute__((ext_vector_type(4))) float f32x4;

#define NF 2
#define NV 4
#define FV 8
#define NE 2048
#define NIN 512
#define NOUT 512
#define NM 514

// ws layout (bytes)
#define WS_P1      0u         // 64 slots, stride 8 floats (32B) = 2048 B
#define WS_P2      2048u      // 32 slots * 32B = 1024 B
#define WS_P3      3072u      // 1024 B
#define WS_COLMIN  4096u      // 512 f = 2048 B
#define WS_G       6144u      // 514 f (pad to 2176)
#define WS_GN      8320u      // 512 f = 2048 B
#define WS_ETA     10368u     // 512 float4 = 8192 B
#define WS_DENOM   18560u     // 8*512 f = 16384 B
#define WS_BIASZ   34944u     // 16384 B
#define WS_BIAST   51328u     // 16384 B
#define WS_THETA   67712u     // 514*512 f = 1052672 B
#define WS_ABF     1120384u   // 8*2048*512 u16 = 16777216 B
#define WS_BZT     17897600u  // 8*512*512 u16 = 4194304 B
#define WS_BTT     22091904u  // 4194304 B -> end 26286208

__constant__ float c_etas[4][4] = {
    {0.05f, 0.90f, 0.20f, 8.0f},
    {0.10f, 0.80f, 0.30f, 5.0f},
    {0.00f, 1.00f, 0.25f, 10.0f},
    {0.15f, 0.70f, 0.15f, 6.0f}};

__device__ __forceinline__ u16 f2bf(float x) {
    unsigned u = __float_as_uint(x);
    unsigned r = (u + 0x7fffu + ((u >> 16) & 1u)) >> 16;
    return (u16)r;
}

__device__ __forceinline__ void gll16(const void* g, void* l) {
    __builtin_amdgcn_global_load_lds((__attribute__((address_space(1))) void*)g,
                                     (__attribute__((address_space(3))) void*)l,
                                     16, 0, 0);
}

// ---- k1: theta_t + colmin (block-local) + G row-sums + Gn col-sums ----
// 8 blocks, each owns 64 columns over all 514 rows. No same-address contention:
// colmin/Gn direct store; G gets 8 atomics/address (one per block).
__global__ void k_theta(const float* __restrict__ theta_, float* __restrict__ theta_t,
                        float* __restrict__ colmin, float* __restrict__ G,
                        float* __restrict__ Gn) {
    int t = threadIdx.x;
    int nl = t & 63, mg = t >> 6;
    int n = blockIdx.x * 64 + nl;
    float mymin = 3.4e38f;
    for (int m = mg; m < NM; m += 4) {
        float thc = fminf(fmaxf(theta_[m * NOUT + n], -10.f), 10.f);
        float gi = fabsf(thc);
        theta_t[m * NOUT + n] = (gi < 0.01f) ? 0.f : thc;
        mymin = fminf(mymin, gi);
    }
    __shared__ float mn[4][64];
    __shared__ float rmin[64];
    mn[mg][nl] = mymin;
    __syncthreads();
    if (mg == 0) {
        float m0 = fminf(fminf(mn[0][nl], mn[1][nl]), fminf(mn[2][nl], mn[3][nl]));
        colmin[n] = m0;
        rmin[nl] = m0;
    }
    __syncthreads();
    float scale = 1e-4f / rmin[nl];
    float gn_acc = 0.f;
    for (int m = mg; m < NM; m += 4) {
        float thc = fminf(fmaxf(theta_[m * NOUT + n], -10.f), 10.f);
        float gt = fabsf(thc) * scale;
        gn_acc += gt;
        float s = gt;  // wave = 64 lanes sharing this m (one m-group per wave)
        for (int off = 32; off > 0; off >>= 1) s += __shfl_down(s, off);
        if (nl == 0) atomicAdd(&G[m], s);
    }
    __shared__ float gnl[4][64];
    gnl[mg][nl] = gn_acc;
    __syncthreads();
    if (mg == 0) Gn[n] = gnl[0][nl] + gnl[1][nl] + gnl[2][nl] + gnl[3][nl];
}

// ---- k1d: gumbel argmax -> per-column activation params ----
__global__ void k_etasel(const float* __restrict__ coeff, const float* __restrict__ gumb,
                         float4* __restrict__ eta4) {
    int n = blockIdx.x * 256 + threadIdx.x;
    if (n >= NOUT) return;
    float best = -1e30f;
    int bi = 0;
    for (int i = 0; i < 4; i++) {
        float c = fminf(fmaxf(coeff[i * NOUT + n], -1.f), 1.f);
        float u = gumb[i * NOUT + n];
        float g = -logf(-logf(u + 1e-20f) + 1e-20f);
        float v = c + g;
        if (v > best) { best = v; bi = i; }
    }
    eta4[n] = make_float4(c_etas[bi][0], c_etas[bi][1], c_etas[bi][2], c_etas[bi][3]);
}

// ---- k2a: denom[fv][n] = sum_m |theta_t[m,n] * fac| ----
__global__ void k_denom(const float* __restrict__ theta_t, const float* __restrict__ noise,
                        float* __restrict__ denom) {
    int fv = blockIdx.z, mc = blockIdx.y, nc = blockIdx.x;
    int t = threadIdx.x;
    int nl = t & 63, mg = t >> 6;
    int n = nc * 64 + nl;
    int mbase = mc * 128 + mg * 32;
    float acc = 0.f;
    for (int i = 0; i < 32; i++) {
        int m = mbase + i;
        if (m < NM) {
            float fac = noise[(fv * NM + m) * NOUT + n] * 0.2f + 0.9f;
            acc += fabsf(theta_t[m * NOUT + n] * fac);
        }
    }
    __shared__ float red[256];
    red[t] = acc;
    __syncthreads();
    if (t < 64)
        atomicAdd(&denom[fv * NOUT + n], red[t] + red[t + 64] + red[t + 128] + red[t + 192]);
}

// ---- k2b: build transposed bf16 B-matrices + fp32 bias rows ----
__global__ void k_wmat(const float* __restrict__ theta_t, const float* __restrict__ theta_,
                       const float* __restrict__ colmin, const float* __restrict__ noise,
                       const float* __restrict__ denom,
                       u16* __restrict__ BzT, u16* __restrict__ BtT,
                       float* __restrict__ bias_z, float* __restrict__ bias_t) {
    int fv = blockIdx.z, mt = blockIdx.y, nt = blockIdx.x;
    int t = threadIdx.x;
    int nl = t & 63, rg = t >> 6;
    __shared__ u16 Wl[64][68];
    __shared__ u16 Sl[64][68];
    int n = nt * 64 + nl;
    float rdv = 1.f / (denom[fv * NOUT + n] + 1e-10f);
    float scale = 1e-4f / colmin[n];
    for (int r = 0; r < 16; r++) {
        int ml = rg * 16 + r;
        int m = mt * 64 + ml;
        if (m < 513) {
            float fac = noise[(fv * NM + m) * NOUT + n] * 0.2f + 0.9f;
            float th = theta_t[m * NOUT + n] * fac;
            float sg = (th >= 0.f) ? 1.f : -1.f;
            float thc = fminf(fmaxf(theta_[m * NOUT + n], -10.f), 10.f);
            float gt = fabsf(thc) * scale;
            if (m == 512) {
                bias_z[fv * NOUT + n] = th * rdv;
                bias_t[fv * NOUT + n] = sg * gt;
            } else {
                Wl[ml][nl] = f2bf(th * rdv);
                Sl[ml][nl] = f2bf(sg * gt);
            }
        }
    }
    __syncthreads();
    if (mt < 8) {
        for (int r = 0; r < 16; r++) {
            int nl2 = rg * 16 + r;
            int ml2 = t & 63;
            int gidx = (fv * NOUT + nt * 64 + nl2) * NIN + mt * 64 + ml2;
            BzT[gidx] = Wl[ml2][nl2];
            BtT[gidx] = Sl[ml2][nl2];
        }
    }
}

// ---- k3: convert A to bf16 + p1 partial (sum a^2 * G[k]); spread atomic slots ----
__global__ void k_prepA(const float* __restrict__ a_prev, const float* __restrict__ G,
                        u16* __restrict__ Abf, float* __restrict__ p1slot) {
    int t = threadIdx.x;
    float acc = 0.f;
#pragma unroll
    for (int i = 0; i < 4; i++) {
        int idx = (i * 2048 + blockIdx.x) * 256 + t;  // 2048 blocks * 4 iters = 2,097,152 float4s
        float4 v = ((const float4*)a_prev)[idx];
        int k = (idx & 127) << 2;
        float4 g4 = *((const float4*)(G + k));
        acc += v.x * v.x * g4.x + v.y * v.y * g4.y + v.z * v.z * g4.z + v.w * v.w * g4.w;
        ushort4 o;
        o.x = f2bf(v.x); o.y = f2bf(v.y); o.z = f2bf(v.z); o.w = f2bf(v.w);
        ((ushort4*)Abf)[idx] = o;
    }
    for (int off = 32; off > 0; off >>= 1) acc += __shfl_down(acc, off);
    __shared__ float red[4];
    int lane = t & 63, wv = t >> 6;
    if (lane == 0) red[wv] = acc;
    __syncthreads();
    if (t == 0)
        atomicAdd(&p1slot[(blockIdx.x & 63) * 8], red[0] + red[1] + red[2] + red[3]);
}

// ---- k4: fused dual-B MFMA GEMM + activation epilogue + power reductions ----
__global__ __launch_bounds__(256, 2) void k_gemm(
    const u16* __restrict__ Abf, const u16* __restrict__ BzT, const u16* __restrict__ BtT,
    const float* __restrict__ bias_z, const float* __restrict__ bias_t,
    const float* __restrict__ Gn, const float4* __restrict__ eta4,
    float* __restrict__ out, float* __restrict__ p2slot, float* __restrict__ p3slot) {
    __shared__ alignas(16) u16 As[128 * 32];
    __shared__ alignas(16) u16 Bzs[128 * 32];
    __shared__ alignas(16) u16 Bts[128 * 32];
    const int tid = threadIdx.x;
    const int lane = tid & 63;
    const int wv = tid >> 6;
    const int wr = wv >> 1, wc = wv & 1;
    const int fv = blockIdx.z;
    const int e0 = blockIdx.y * 128;
    const int n0 = blockIdx.x * 128;

    const u16* Ag = Abf + (fv * NE + e0) * NIN;
    const u16* Bzg = BzT + (fv * NOUT + n0) * NIN;
    const u16* Btg = BtT + (fv * NOUT + n0) * NIN;

    f32x4 accz[4][4], acct[4][4];
#pragma unroll
    for (int i = 0; i < 4; i++)
#pragma unroll
        for (int j = 0; j < 4; j++) {
            f32x4 zz = {0.f, 0.f, 0.f, 0.f};
            accz[i][j] = zz;
            acct[i][j] = zz;
        }

    const int r0 = tid >> 2;        // staging row 0..63
    const int c0 = (tid & 3) * 8;   // k-chunk element offset

    for (int k0 = 0; k0 < 512; k0 += 32) {
        gll16(Ag + r0 * 512 + k0 + c0, (u16*)As + tid * 8);
        gll16(Ag + (r0 + 64) * 512 + k0 + c0, (u16*)As + tid * 8 + 2048);
        gll16(Bzg + r0 * 512 + k0 + c0, (u16*)Bzs + tid * 8);
        gll16(Bzg + (r0 + 64) * 512 + k0 + c0, (u16*)Bzs + tid * 8 + 2048);
        gll16(Btg + r0 * 512 + k0 + c0, (u16*)Bts + tid * 8);
        gll16(Btg + (r0 + 64) * 512 + k0 + c0, (u16*)Bts + tid * 8 + 2048);
        __builtin_amdgcn_s_waitcnt(0);
        __syncthreads();
        const int kof = (lane >> 4) * 8;
        const int rA = wr * 64 + (lane & 15);
        const int rB = wc * 64 + (lane & 15);
        short8 af[4], bzf[4], btf[4];
#pragma unroll
        for (int i = 0; i < 4; i++) af[i] = *(const short8*)(As + (rA + i * 16) * 32 + kof);
#pragma unroll
        for (int j = 0; j < 4; j++) {
            bzf[j] = *(const short8*)(Bzs + (rB + j * 16) * 32 + kof);
            btf[j] = *(const short8*)(Bts + (rB + j * 16) * 32 + kof);
        }
#pragma unroll
        for (int i = 0; i < 4; i++)
#pragma unroll
            for (int j = 0; j < 4; j++) {
                accz[i][j] = __builtin_amdgcn_mfma_f32_16x16x32_bf16(af[i], bzf[j], accz[i][j], 0, 0, 0);
                acct[i][j] = __builtin_amdgcn_mfma_f32_16x16x32_bf16(af[i], btf[j], acct[i][j], 0, 0, 0);
            }
        __syncthreads();
    }

    // epilogue: C/D layout col=lane&15, row=(lane>>4)*4+reg (m89-verified)
    float p2 = 0.f, p3 = 0.f;
    const int col = lane & 15;
    const int rowq = (lane >> 4) * 4;
#pragma unroll
    for (int j = 0; j < 4; j++) {
        int n = n0 + wc * 64 + j * 16 + col;
        float bz = bias_z[fv * NOUT + n];
        float bt = bias_t[fv * NOUT + n];
        float gnv = Gn[n];
        float4 e4 = eta4[n];
#pragma unroll
        for (int i = 0; i < 4; i++) {
            int ebase = e0 + wr * 64 + i * 16 + rowq;
#pragma unroll
            for (int r = 0; r < 4; r++) {
                float z = accz[i][j][r] + bz;
                float t = acct[i][j][r] + bt;
                p2 += z * t;
                p3 += z * z * gnv;
                float x = (z - e4.z) * e4.w;
                float ex = __expf(2.f * x);
                float th = 1.f - 2.f / (ex + 1.f);
                out[(fv * NE + ebase + r) * NOUT + n] = e4.x + e4.y * th;
            }
        }
    }
    for (int off = 32; off > 0; off >>= 1) {
        p2 += __shfl_down(p2, off);
        p3 += __shfl_down(p3, off);
    }
    __shared__ float r2[4], r3[4];
    if (lane == 0) { r2[wv] = p2; r3[wv] = p3; }
    __syncthreads();
    if (tid == 0) {
        int slot = ((blockIdx.x + blockIdx.y * 4 + blockIdx.z * 64) & 31) * 8;
        atomicAdd(&p2slot[slot], r2[0] + r2[1] + r2[2] + r2[3]);
        atomicAdd(&p3slot[slot], r3[0] + r3[1] + r3[2] + r3[3]);
    }
}

// ---- k5: sum slots, combine power terms ----
__global__ void k_final(const float* __restrict__ p1s, const float* __restrict__ p2s,
                        const float* __restrict__ p3s, const float* __restrict__ G,
                        float* __restrict__ out) {
    int t = threadIdx.x;  // 64
    float s1 = p1s[t * 8];
    float s2 = (t < 32) ? p2s[t * 8] : 0.f;
    float s3 = (t < 32) ? p3s[t * 8] : 0.f;
    for (int off = 32; off > 0; off >>= 1) {
        s1 += __shfl_down(s1, off);
        s2 += __shfl_down(s2, off);
        s3 += __shfl_down(s3, off);
    }
    if (t == 0) {
        float mp = (s1 + 16384.f * G[512] - 2.f * s2 + s3) * (1.f / 16384.f);
        out[8388608] = mp;
    }
}

extern "C" void kernel_launch(void* const* d_in, const int* in_sizes, int n_in,
                              void* d_out, int out_size, void* d_ws, size_t ws_size,
                              hipStream_t stream) {
    const float* a_prev = (const float*)d_in[0];
    const float* theta_ = (const float*)d_in[1];
    const float* coeff = (const float*)d_in[2];
    const float* noise = (const float*)d_in[3];
    const float* gumb = (const float*)d_in[4];
    float* out = (float*)d_out;
    char* w = (char*)d_ws;
    float* p1s = (float*)(w + WS_P1);
    float* p2s = (float*)(w + WS_P2);
    float* p3s = (float*)(w + WS_P3);
    float* colmin = (float*)(w + WS_COLMIN);
    float* G = (float*)(w + WS_G);
    float* Gn = (float*)(w + WS_GN);
    float4* eta4 = (float4*)(w + WS_ETA);
    float* denom = (float*)(w + WS_DENOM);
    float* bias_z = (float*)(w + WS_BIASZ);
    float* bias_t = (float*)(w + WS_BIAST);
    float* theta_t = (float*)(w + WS_THETA);
    u16* Abf = (u16*)(w + WS_ABF);
    u16* BzT = (u16*)(w + WS_BZT);
    u16* BtT = (u16*)(w + WS_BTT);

    hipMemsetAsync(w + WS_P1, 0, 4096, stream);       // p1/p2/p3 slots
    hipMemsetAsync(w + WS_G, 0, 2176, stream);        // G
    hipMemsetAsync(w + WS_DENOM, 0, 16384, stream);   // denom

    k_theta<<<8, 256, 0, stream>>>(theta_, theta_t, colmin, G, Gn);
    k_etasel<<<2, 256, 0, stream>>>(coeff, gumb, eta4);
    k_denom<<<dim3(8, 5, FV), 256, 0, stream>>>(theta_t, noise, denom);
    k_wmat<<<dim3(8, 9, FV), 256, 0, stream>>>(theta_t, theta_, colmin, noise, denom,
                                               BzT, BtT, bias_z, bias_t);
    k_prepA<<<2048, 256, 0, stream>>>(a_prev, G, Abf, p1s);
    k_gemm<<<dim3(4, 16, FV), 256, 0, stream>>>(Abf, BzT, BtT, bias_z, bias_t, Gn, eta4,
                                                out, p2s, p3s);
    k_final<<<1, 64, 0, stream>>>(p1s, p2s, p3s, G, out);
}

// Round 3
// 165.106 us; speedup vs baseline: 1.9966x; 1.5603x over previous
//
#include <hip/hip_runtime.h>

typedef unsigned short u16;
typedef __attribute__((ext_vector_type(8))) short short8;
typedef __attribute__((ext_vector_type(4))) float f32x4;

#define NF 2
#define NV 4
#define FV 8
#define NE 2048
#define NIN 512
#define NOUT 512
#define NM 514

// ws layout (bytes)
#define WS_P1      0u         // 64 slots, stride 8 floats (32B)
#define WS_P2      2048u      // 32 slots * 32B
#define WS_P3      3072u
#define WS_SCALE   4096u      // 512 f  (scale = 1e-4/colmin)
#define WS_G       6144u      // 514 f (pad 2176)
#define WS_GN      8320u      // 512 f
#define WS_ETA     10368u     // 512 float4
#define WS_DENOM   18560u     // 8*512 f
#define WS_BIASZ   34944u
#define WS_BIAST   51328u
#define WS_PMIN    67712u     // 64*512 f = 131072
#define WS_PSUM    198784u    // 131072
#define WS_ABF     329856u    // 8*2048*512 u16 = 16777216
#define WS_BZT     17107072u  // 8*512*512 u16 = 4194304
#define WS_BTT     21301376u  // 4194304 -> end 25495680

__constant__ float c_etas[4][4] = {
    {0.05f, 0.90f, 0.20f, 8.0f},
    {0.10f, 0.80f, 0.30f, 5.0f},
    {0.00f, 1.00f, 0.25f, 10.0f},
    {0.15f, 0.70f, 0.15f, 6.0f}};

__device__ __forceinline__ u16 f2bf(float x) {
    unsigned u = __float_as_uint(x);
    unsigned r = (u + 0x7fffu + ((u >> 16) & 1u)) >> 16;
    return (u16)r;
}

__device__ __forceinline__ void gll16(const void* g, void* l) {
    __builtin_amdgcn_global_load_lds((__attribute__((address_space(1))) void*)g,
                                     (__attribute__((address_space(3))) void*)l,
                                     16, 0, 0);
}

// ---- kA: per-column partial min/sum of g_init over 9-row strips ----
__global__ void kA_part(const float* __restrict__ theta_, float* __restrict__ pmin,
                        float* __restrict__ psum) {
    int t = threadIdx.x;
    int n2 = t * 2;
    int r0 = blockIdx.x * 9;  // 64 blocks * 9 = 576 >= 514
    float mn0 = 3.4e38f, mn1 = 3.4e38f, s0 = 0.f, s1 = 0.f;
    int rend = r0 + 9;
    if (rend > NM) rend = NM;
    for (int r = r0; r < rend; r++) {
        float2 v = *(const float2*)(theta_ + r * NOUT + n2);
        float a0 = fabsf(fminf(fmaxf(v.x, -10.f), 10.f));
        float a1 = fabsf(fminf(fmaxf(v.y, -10.f), 10.f));
        mn0 = fminf(mn0, a0); mn1 = fminf(mn1, a1);
        s0 += a0; s1 += a1;
    }
    *(float2*)(pmin + blockIdx.x * NOUT + n2) = make_float2(mn0, mn1);
    *(float2*)(psum + blockIdx.x * NOUT + n2) = make_float2(s0, s1);
}

// ---- kB: fold partials -> scale[n], Gn[n] ----
__global__ void kB_fold(const float* __restrict__ pmin, const float* __restrict__ psum,
                        float* __restrict__ scale, float* __restrict__ Gn) {
    int n = threadIdx.x;  // 512
    float mn = 3.4e38f, s = 0.f;
    for (int i = 0; i < 64; i++) {
        mn = fminf(mn, pmin[i * NOUT + n]);
        s += psum[i * NOUT + n];
    }
    float sc = 1e-4f / mn;
    scale[n] = sc;
    Gn[n] = sc * s;
}

// ---- kC: G[m] = sum_n g_init[m,n]*scale[n], one row per block (1 wave) ----
__global__ void kC_grow(const float* __restrict__ theta_, const float* __restrict__ scale,
                        float* __restrict__ G) {
    int m = blockIdx.x;
    int t = threadIdx.x;  // 64
    const float4* rowp = (const float4*)(theta_ + m * NOUT);
    const float4* scp = (const float4*)scale;
    float acc = 0.f;
#pragma unroll
    for (int i = 0; i < 2; i++) {
        float4 v = rowp[t * 2 + i];
        float4 s = scp[t * 2 + i];
        acc += fabsf(fminf(fmaxf(v.x, -10.f), 10.f)) * s.x
             + fabsf(fminf(fmaxf(v.y, -10.f), 10.f)) * s.y
             + fabsf(fminf(fmaxf(v.z, -10.f), 10.f)) * s.z
             + fabsf(fminf(fmaxf(v.w, -10.f), 10.f)) * s.w;
    }
    for (int off = 32; off > 0; off >>= 1) acc += __shfl_down(acc, off);
    if (t == 0) G[m] = acc;
}

// ---- k1d: gumbel argmax -> per-column activation params ----
__global__ void k_etasel(const float* __restrict__ coeff, const float* __restrict__ gumb,
                         float4* __restrict__ eta4) {
    int n = blockIdx.x * 256 + threadIdx.x;
    if (n >= NOUT) return;
    float best = -1e30f;
    int bi = 0;
    for (int i = 0; i < 4; i++) {
        float c = fminf(fmaxf(coeff[i * NOUT + n], -1.f), 1.f);
        float u = gumb[i * NOUT + n];
        float g = -logf(-logf(u + 1e-20f) + 1e-20f);
        float v = c + g;
        if (v > best) { best = v; bi = i; }
    }
    eta4[n] = make_float4(c_etas[bi][0], c_etas[bi][1], c_etas[bi][2], c_etas[bi][3]);
}

// ---- k2a: denom[fv][n] = sum_m |theta_t[m,n] * fac| ----
__global__ void k_denom(const float* __restrict__ theta_, const float* __restrict__ noise,
                        float* __restrict__ denom) {
    int fv = blockIdx.z, mc = blockIdx.y, nc = blockIdx.x;
    int t = threadIdx.x;
    int nl = t & 63, mg = t >> 6;
    int n = nc * 64 + nl;
    int mbase = mc * 128 + mg * 32;
    float acc = 0.f;
    for (int i = 0; i < 32; i++) {
        int m = mbase + i;
        if (m < NM) {
            float fac = noise[(fv * NM + m) * NOUT + n] * 0.2f + 0.9f;
            float thc = fminf(fmaxf(theta_[m * NOUT + n], -10.f), 10.f);
            float tht = (fabsf(thc) < 0.01f) ? 0.f : thc;
            acc += fabsf(tht * fac);
        }
    }
    __shared__ float red[256];
    red[t] = acc;
    __syncthreads();
    if (t < 64)
        atomicAdd(&denom[fv * NOUT + n], red[t] + red[t + 64] + red[t + 128] + red[t + 192]);
}

// ---- k2b: build transposed bf16 B-matrices + fp32 bias rows ----
__global__ void k_wmat(const float* __restrict__ theta_, const float* __restrict__ scale,
                       const float* __restrict__ noise, const float* __restrict__ denom,
                       u16* __restrict__ BzT, u16* __restrict__ BtT,
                       float* __restrict__ bias_z, float* __restrict__ bias_t) {
    int fv = blockIdx.z, mt = blockIdx.y, nt = blockIdx.x;
    int t = threadIdx.x;
    int nl = t & 63, rg = t >> 6;
    __shared__ u16 Wl[64][68];
    __shared__ u16 Sl[64][68];
    int n = nt * 64 + nl;
    float rdv = 1.f / (denom[fv * NOUT + n] + 1e-10f);
    float sc = scale[n];
    for (int r = 0; r < 16; r++) {
        int ml = rg * 16 + r;
        int m = mt * 64 + ml;
        if (m < 513) {
            float fac = noise[(fv * NM + m) * NOUT + n] * 0.2f + 0.9f;
            float thc = fminf(fmaxf(theta_[m * NOUT + n], -10.f), 10.f);
            float gi = fabsf(thc);
            float tht = (gi < 0.01f) ? 0.f : thc;
            float th = tht * fac;
            float sg = (th >= 0.f) ? 1.f : -1.f;
            float gt = gi * sc;
            if (m == 512) {
                bias_z[fv * NOUT + n] = th * rdv;
                bias_t[fv * NOUT + n] = sg * gt;
            } else {
                Wl[ml][nl] = f2bf(th * rdv);
                Sl[ml][nl] = f2bf(sg * gt);
            }
        }
    }
    __syncthreads();
    if (mt < 8) {
        for (int r = 0; r < 16; r++) {
            int nl2 = rg * 16 + r;
            int ml2 = t & 63;
            int gidx = (fv * NOUT + nt * 64 + nl2) * NIN + mt * 64 + ml2;
            BzT[gidx] = Wl[ml2][nl2];
            BtT[gidx] = Sl[ml2][nl2];
        }
    }
}

// ---- k3: convert A to bf16 + p1 partial (sum a^2 * G[k]); spread atomic slots ----
__global__ void k_prepA(const float* __restrict__ a_prev, const float* __restrict__ G,
                        u16* __restrict__ Abf, float* __restrict__ p1slot) {
    int t = threadIdx.x;
    float acc = 0.f;
#pragma unroll
    for (int i = 0; i < 4; i++) {
        int idx = (i * 2048 + blockIdx.x) * 256 + t;
        float4 v = ((const float4*)a_prev)[idx];
        int k = (idx & 127) << 2;
        float4 g4 = *((const float4*)(G + k));
        acc += v.x * v.x * g4.x + v.y * v.y * g4.y + v.z * v.z * g4.z + v.w * v.w * g4.w;
        ushort4 o;
        o.x = f2bf(v.x); o.y = f2bf(v.y); o.z = f2bf(v.z); o.w = f2bf(v.w);
        ((ushort4*)Abf)[idx] = o;
    }
    for (int off = 32; off > 0; off >>= 1) acc += __shfl_down(acc, off);
    __shared__ float red[4];
    int lane = t & 63, wv = t >> 6;
    if (lane == 0) red[wv] = acc;
    __syncthreads();
    if (t == 0)
        atomicAdd(&p1slot[(blockIdx.x & 63) * 8], red[0] + red[1] + red[2] + red[3]);
}

// ---- k4: fused dual-B MFMA GEMM + activation epilogue + power reductions ----
__global__ __launch_bounds__(256, 2) void k_gemm(
    const u16* __restrict__ Abf, const u16* __restrict__ BzT, const u16* __restrict__ BtT,
    const float* __restrict__ bias_z, const float* __restrict__ bias_t,
    const float* __restrict__ Gn, const float4* __restrict__ eta4,
    float* __restrict__ out, float* __restrict__ p2slot, float* __restrict__ p3slot) {
    __shared__ alignas(16) u16 As[128 * 32];
    __shared__ alignas(16) u16 Bzs[128 * 32];
    __shared__ alignas(16) u16 Bts[128 * 32];
    const int tid = threadIdx.x;
    const int lane = tid & 63;
    const int wv = tid >> 6;
    const int wr = wv >> 1, wc = wv & 1;
    const int fv = blockIdx.z;
    const int e0 = blockIdx.y * 128;
    const int n0 = blockIdx.x * 128;

    const u16* Ag = Abf + (fv * NE + e0) * NIN;
    const u16* Bzg = BzT + (fv * NOUT + n0) * NIN;
    const u16* Btg = BtT + (fv * NOUT + n0) * NIN;

    f32x4 accz[4][4], acct[4][4];
#pragma unroll
    for (int i = 0; i < 4; i++)
#pragma unroll
        for (int j = 0; j < 4; j++) {
            f32x4 zz = {0.f, 0.f, 0.f, 0.f};
            accz[i][j] = zz;
            acct[i][j] = zz;
        }

    const int r0 = tid >> 2;
    const int c0 = (tid & 3) * 8;

    for (int k0 = 0; k0 < 512; k0 += 32) {
        gll16(Ag + r0 * 512 + k0 + c0, (u16*)As + tid * 8);
        gll16(Ag + (r0 + 64) * 512 + k0 + c0, (u16*)As + tid * 8 + 2048);
        gll16(Bzg + r0 * 512 + k0 + c0, (u16*)Bzs + tid * 8);
        gll16(Bzg + (r0 + 64) * 512 + k0 + c0, (u16*)Bzs + tid * 8 + 2048);
        gll16(Btg + r0 * 512 + k0 + c0, (u16*)Bts + tid * 8);
        gll16(Btg + (r0 + 64) * 512 + k0 + c0, (u16*)Bts + tid * 8 + 2048);
        __builtin_amdgcn_s_waitcnt(0);
        __syncthreads();
        const int kof = (lane >> 4) * 8;
        const int rA = wr * 64 + (lane & 15);
        const int rB = wc * 64 + (lane & 15);
        short8 af[4], bzf[4], btf[4];
#pragma unroll
        for (int i = 0; i < 4; i++) af[i] = *(const short8*)(As + (rA + i * 16) * 32 + kof);
#pragma unroll
        for (int j = 0; j < 4; j++) {
            bzf[j] = *(const short8*)(Bzs + (rB + j * 16) * 32 + kof);
            btf[j] = *(const short8*)(Bts + (rB + j * 16) * 32 + kof);
        }
#pragma unroll
        for (int i = 0; i < 4; i++)
#pragma unroll
            for (int j = 0; j < 4; j++) {
                accz[i][j] = __builtin_amdgcn_mfma_f32_16x16x32_bf16(af[i], bzf[j], accz[i][j], 0, 0, 0);
                acct[i][j] = __builtin_amdgcn_mfma_f32_16x16x32_bf16(af[i], btf[j], acct[i][j], 0, 0, 0);
            }
        __syncthreads();
    }

    float p2 = 0.f, p3 = 0.f;
    const int col = lane & 15;
    const int rowq = (lane >> 4) * 4;
#pragma unroll
    for (int j = 0; j < 4; j++) {
        int n = n0 + wc * 64 + j * 16 + col;
        float bz = bias_z[fv * NOUT + n];
        float bt = bias_t[fv * NOUT + n];
        float gnv = Gn[n];
        float4 e4 = eta4[n];
#pragma unroll
        for (int i = 0; i < 4; i++) {
            int ebase = e0 + wr * 64 + i * 16 + rowq;
#pragma unroll
            for (int r = 0; r < 4; r++) {
                float z = accz[i][j][r] + bz;
                float t = acct[i][j][r] + bt;
                p2 += z * t;
                p3 += z * z * gnv;
                float x = (z - e4.z) * e4.w;
                float ex = __expf(2.f * x);
                float th = 1.f - 2.f / (ex + 1.f);
                out[(fv * NE + ebase + r) * NOUT + n] = e4.x + e4.y * th;
            }
        }
    }
    for (int off = 32; off > 0; off >>= 1) {
        p2 += __shfl_down(p2, off);
        p3 += __shfl_down(p3, off);
    }
    __shared__ float r2[4], r3[4];
    if (lane == 0) { r2[wv] = p2; r3[wv] = p3; }
    __syncthreads();
    if (tid == 0) {
        int slot = ((blockIdx.x + blockIdx.y * 4 + blockIdx.z * 64) & 31) * 8;
        atomicAdd(&p2slot[slot], r2[0] + r2[1] + r2[2] + r2[3]);
        atomicAdd(&p3slot[slot], r3[0] + r3[1] + r3[2] + r3[3]);
    }
}

// ---- k5: sum slots, combine power terms ----
__global__ void k_final(const float* __restrict__ p1s, const float* __restrict__ p2s,
                        const float* __restrict__ p3s, const float* __restrict__ G,
                        float* __restrict__ out) {
    int t = threadIdx.x;  // 64
    float s1 = p1s[t * 8];
    float s2 = (t < 32) ? p2s[t * 8] : 0.f;
    float s3 = (t < 32) ? p3s[t * 8] : 0.f;
    for (int off = 32; off > 0; off >>= 1) {
        s1 += __shfl_down(s1, off);
        s2 += __shfl_down(s2, off);
        s3 += __shfl_down(s3, off);
    }
    if (t == 0) {
        float mp = (s1 + 16384.f * G[512] - 2.f * s2 + s3) * (1.f / 16384.f);
        out[8388608] = mp;
    }
}

extern "C" void kernel_launch(void* const* d_in, const int* in_sizes, int n_in,
                              void* d_out, int out_size, void* d_ws, size_t ws_size,
                              hipStream_t stream) {
    const float* a_prev = (const float*)d_in[0];
    const float* theta_ = (const float*)d_in[1];
    const float* coeff = (const float*)d_in[2];
    const float* noise = (const float*)d_in[3];
    const float* gumb = (const float*)d_in[4];
    float* out = (float*)d_out;
    char* w = (char*)d_ws;
    float* p1s = (float*)(w + WS_P1);
    float* p2s = (float*)(w + WS_P2);
    float* p3s = (float*)(w + WS_P3);
    float* scale = (float*)(w + WS_SCALE);
    float* G = (float*)(w + WS_G);
    float* Gn = (float*)(w + WS_GN);
    float4* eta4 = (float4*)(w + WS_ETA);
    float* denom = (float*)(w + WS_DENOM);
    float* bias_z = (float*)(w + WS_BIASZ);
    float* bias_t = (float*)(w + WS_BIAST);
    float* pmin = (float*)(w + WS_PMIN);
    float* psum = (float*)(w + WS_PSUM);
    u16* Abf = (u16*)(w + WS_ABF);
    u16* BzT = (u16*)(w + WS_BZT);
    u16* BtT = (u16*)(w + WS_BTT);

    hipMemsetAsync(w + WS_P1, 0, 4096, stream);      // p1/p2/p3 slots
    hipMemsetAsync(w + WS_DENOM, 0, 16384, stream);  // denom

    kA_part<<<64, 256, 0, stream>>>(theta_, pmin, psum);
    kB_fold<<<1, 512, 0, stream>>>(pmin, psum, scale, Gn);
    kC_grow<<<514, 64, 0, stream>>>(theta_, scale, G);
    k_etasel<<<2, 256, 0, stream>>>(coeff, gumb, eta4);
    k_denom<<<dim3(8, 5, FV), 256, 0, stream>>>(theta_, noise, denom);
    k_wmat<<<dim3(8, 9, FV), 256, 0, stream>>>(theta_, scale, noise, denom,
                                               BzT, BtT, bias_z, bias_t);
    k_prepA<<<2048, 256, 0, stream>>>(a_prev, G, Abf, p1s);
    k_gemm<<<dim3(4, 16, FV), 256, 0, stream>>>(Abf, BzT, BtT, bias_z, bias_t, Gn, eta4,
                                                out, p2s, p3s);
    k_final<<<1, 64, 0, stream>>>(p1s, p2s, p3s, G, out);
}